// Round 18
// baseline (402.214 us; speedup 1.0000x reference)
//
#include <hip/hip_runtime.h>

typedef __bf16 bf16x8 __attribute__((ext_vector_type(8)));
typedef __bf16 bf16x4 __attribute__((ext_vector_type(4)));
typedef float  f32x4  __attribute__((ext_vector_type(4)));

#define MFMA16(a, b, c) __builtin_amdgcn_mfma_f32_16x16x32_bf16((a), (b), (c), 0, 0, 0)

// ---- problem geometry ----
constexpr int Cdim = 192, NHd = 6;
constexpr int Dd = 46, Hh = 47, Wl = 48;
constexpr int HWst = Hh * Wl;            // 2256
constexpr int NWIN_PER_B = 12 * 12 * 12; // 1728
constexpr int NBLK = 2 * NWIN_PER_B;     // 3456 windows
constexpr int NPAIR = NBLK / 2;          // 1728 blocks (2 windows each)
constexpr float SCALE = 0.17677669529663687f;  // 32^-0.5

// ---- workspace: converted weights + transposed bias table only ----
constexpr int WQ_ELEMS = 576 * 192;
constexpr int WP_ELEMS = 192 * 192;
constexpr size_t OFF_WQ   = 0;
constexpr size_t OFF_WP   = OFF_WQ + WQ_ELEMS;
constexpr size_t OFF_RPBT = OFF_WP + WP_ELEMS;
constexpr size_t WS_SMALL = (OFF_RPBT + 4128) * 2;

__device__ inline bf16x8 cvt8(const float* __restrict__ p) {
  f32x4 u0 = *(const f32x4*)p;
  f32x4 u1 = *(const f32x4*)(p + 4);
  bf16x8 r;
  r[0] = (__bf16)u0[0]; r[1] = (__bf16)u0[1]; r[2] = (__bf16)u0[2]; r[3] = (__bf16)u0[3];
  r[4] = (__bf16)u1[0]; r[5] = (__bf16)u1[1]; r[6] = (__bf16)u1[2]; r[7] = (__bf16)u1[3];
  return r;
}

__device__ inline bf16x4 pack4(f32x4 v) {
  bf16x4 r;
  r[0] = (__bf16)v[0]; r[1] = (__bf16)v[1]; r[2] = (__bf16)v[2]; r[3] = (__bf16)v[3];
  return r;
}

__device__ inline bf16x8 cat8(bf16x4 a, bf16x4 b) {
  bf16x8 r;
  r[0] = a[0]; r[1] = a[1]; r[2] = a[2]; r[3] = a[3];
  r[4] = b[0]; r[5] = b[1]; r[6] = b[2]; r[7] = b[3];
  return r;
}

__global__ __launch_bounds__(256) void convert_w_kernel(
    const float* __restrict__ qkv_w, const float* __restrict__ proj_w,
    const float* __restrict__ rpb,
    __bf16* __restrict__ wq, __bf16* __restrict__ wp, float* __restrict__ rpbt) {
  const int i = blockIdx.x * 256 + threadIdx.x;
  if (i < WQ_ELEMS) wq[i] = (__bf16)qkv_w[i];
  if (i < WP_ELEMS) wp[i] = (__bf16)proj_w[i];
  if (i < 343 * NHd) {
    const int h = i / 343, idx = i % 343;
    rpbt[h * 343 + idx] = rpb[idx * NHd + h];
  }
}

// ============ Fused kernel: 2 windows/block, rotated LDS regions ============
constexpr int XWA  = 204;  // conflict-free ds_read_b128 stride
constexpr int QKLD = 36;
constexpr int VLD  = 68;
constexpr int BUFE = 2304;               // per-wave repack buf (elems)
constexpr int REGE = 6 * BUFE;           // region size 13824 elems = 27648 B

struct LaneCtx {
  int tid, li, g, hq;
  int b, d0, h0;
};

__device__ inline void stage_x(const float* __restrict__ x, __bf16* __restrict__ xw,
                               const LaneCtx& L, int w0) {
  const f32x4 fz = {0.f, 0.f, 0.f, 0.f};
  #pragma unroll
  for (int rep = 0; rep < 8; ++rep) {
    const int task = rep * 384 + L.tid;
    const int c = task % Cdim, ph = task / Cdim;
    const int dd = ph >> 2, hh = ph & 3;
    const int d = L.d0 + dd, hs = L.h0 + hh;
    f32x4 v = fz;
    if (d < Dd && hs < Hh)
      v = *(const f32x4*)(x + ((size_t)(L.b * Cdim + c) * Dd + d) * HWst + hs * Wl + w0);
    const int nb = (dd * 16 + hh * 4) * XWA + c;
    xw[nb]           = (__bf16)v[0];
    xw[nb + XWA]     = (__bf16)v[1];
    xw[nb + 2 * XWA] = (__bf16)v[2];
    xw[nb + 3 * XWA] = (__bf16)v[3];
  }
}

// q/k/v GEMM + repack + fragment load (reads xw, scratch in bufreg)
__device__ inline void gemm_qkv(const __bf16* __restrict__ xw, __bf16* __restrict__ bufreg,
                                const float* __restrict__ qkv_b, const __bf16* __restrict__ wq,
                                const LaneCtx& L,
                                bf16x8 (&qfv)[4], bf16x8 (&kfv)[4], bf16x8 (&vav)[2][2]) {
  const f32x4 fz = {0.f, 0.f, 0.f, 0.f};
  const int li = L.li, g = L.g, hq = L.hq;
  __bf16* buf = bufreg + hq * BUFE;

  // q part (swapped orientation)
  {
    f32x4 acc[2][4];
    #pragma unroll
    for (int i = 0; i < 2; ++i)
      #pragma unroll
      for (int t = 0; t < 4; ++t) acc[i][t] = fz;
    #pragma unroll
    for (int kk = 0; kk < 6; ++kk) {
      const int k0 = kk * 32 + g * 8;
      bf16x8 xf[4];
      #pragma unroll
      for (int nt = 0; nt < 4; ++nt)
        xf[nt] = *(const bf16x8*)&xw[(nt * 16 + li) * XWA + k0];
      #pragma unroll
      for (int i = 0; i < 2; ++i) {
        bf16x8 wf = *(const bf16x8*)(wq + (size_t)((hq * 2 + i) * 16 + li) * Cdim + k0);
        #pragma unroll
        for (int nt = 0; nt < 4; ++nt)
          acc[i][nt] = MFMA16(wf, xf[nt], acc[i][nt]);
      }
    }
    #pragma unroll
    for (int i = 0; i < 2; ++i) {
      const f32x4 b4 = *(const f32x4*)(qkv_b + (hq * 2 + i) * 16 + g * 4);
      #pragma unroll
      for (int nt = 0; nt < 4; ++nt) {
        f32x4 val = (acc[i][nt] + b4) * SCALE;
        *(bf16x4*)&buf[(nt * 16 + li) * QKLD + i * 16 + g * 4] = pack4(val);
      }
    }
    #pragma unroll
    for (int t = 0; t < 4; ++t) {
      bf16x4 lo = *(const bf16x4*)&buf[(t * 16 + li) * QKLD + g * 8];
      bf16x4 hi = *(const bf16x4*)&buf[(t * 16 + li) * QKLD + g * 8 + 4];
      qfv[t] = cat8(lo, hi);
    }
  }
  // k part
  {
    f32x4 acc[2][4];
    #pragma unroll
    for (int i = 0; i < 2; ++i)
      #pragma unroll
      for (int t = 0; t < 4; ++t) acc[i][t] = fz;
    #pragma unroll
    for (int kk = 0; kk < 6; ++kk) {
      const int k0 = kk * 32 + g * 8;
      bf16x8 xf[4];
      #pragma unroll
      for (int nt = 0; nt < 4; ++nt)
        xf[nt] = *(const bf16x8*)&xw[(nt * 16 + li) * XWA + k0];
      #pragma unroll
      for (int i = 0; i < 2; ++i) {
        bf16x8 wf = *(const bf16x8*)(wq + (size_t)(192 + (hq * 2 + i) * 16 + li) * Cdim + k0);
        #pragma unroll
        for (int nt = 0; nt < 4; ++nt)
          acc[i][nt] = MFMA16(wf, xf[nt], acc[i][nt]);
      }
    }
    #pragma unroll
    for (int i = 0; i < 2; ++i) {
      const f32x4 b4 = *(const f32x4*)(qkv_b + 192 + (hq * 2 + i) * 16 + g * 4);
      #pragma unroll
      for (int nt = 0; nt < 4; ++nt) {
        f32x4 val = acc[i][nt] + b4;
        *(bf16x4*)&buf[(nt * 16 + li) * QKLD + i * 16 + g * 4] = pack4(val);
      }
    }
    #pragma unroll
    for (int t = 0; t < 4; ++t) {
      bf16x4 lo = *(const bf16x4*)&buf[(t * 16 + li) * QKLD + g * 8];
      bf16x4 hi = *(const bf16x4*)&buf[(t * 16 + li) * QKLD + g * 8 + 4];
      kfv[t] = cat8(lo, hi);
    }
  }
  // v part (original orientation), permuted reads for in-register P
  {
    f32x4 acc[2][4];
    #pragma unroll
    for (int i = 0; i < 2; ++i)
      #pragma unroll
      for (int t = 0; t < 4; ++t) acc[i][t] = fz;
    #pragma unroll
    for (int kk = 0; kk < 6; ++kk) {
      const int k0 = kk * 32 + g * 8;
      bf16x8 xf[4];
      #pragma unroll
      for (int rt = 0; rt < 4; ++rt)
        xf[rt] = *(const bf16x8*)&xw[(rt * 16 + li) * XWA + k0];
      #pragma unroll
      for (int i = 0; i < 2; ++i) {
        bf16x8 wf = *(const bf16x8*)(wq + (size_t)(384 + (hq * 2 + i) * 16 + li) * Cdim + k0);
        #pragma unroll
        for (int rt = 0; rt < 4; ++rt)
          acc[i][rt] = MFMA16(xf[rt], wf, acc[i][rt]);
      }
    }
    #pragma unroll
    for (int i = 0; i < 2; ++i) {
      const float bias = qkv_b[384 + (hq * 2 + i) * 16 + li];
      const f32x4 vb = {bias, bias, bias, bias};
      #pragma unroll
      for (int rt = 0; rt < 4; ++rt) {
        f32x4 val = acc[i][rt] + vb;
        *(bf16x4*)&buf[(i * 16 + li) * VLD + rt * 16 + g * 4] = pack4(val);
      }
    }
    #pragma unroll
    for (int rt = 0; rt < 2; ++rt)
      #pragma unroll
      for (int kk = 0; kk < 2; ++kk) {
        bf16x4 lo = *(const bf16x4*)&buf[(rt * 16 + li) * VLD + kk * 32 + g * 4];
        bf16x4 hi = *(const bf16x4*)&buf[(rt * 16 + li) * VLD + kk * 32 + 16 + g * 4];
        vav[rt][kk] = cat8(lo, hi);
      }
  }
}

__device__ inline void attn_phase(__bf16* __restrict__ ao, const LaneCtx& L,
                                  const float (&brow)[7][4],
                                  const bf16x8 (&qfv)[4], const bf16x8 (&kfv)[4],
                                  const bf16x8 (&vav)[2][2]) {
  const f32x4 fz = {0.f, 0.f, 0.f, 0.f};
  const int li = L.li, g = L.g, hq = L.hq;
  #pragma unroll
  for (int rb = 0; rb < 4; ++rb) {
    f32x4 s[4];
    #pragma unroll
    for (int ct = 0; ct < 4; ++ct) s[ct] = MFMA16(kfv[ct], qfv[rb], fz);

    float t[4][4];
    float rm = -3e38f;
    #pragma unroll
    for (int ct = 0; ct < 4; ++ct) {
      #pragma unroll
      for (int r = 0; r < 4; ++r) {
        const float tv = s[ct][r] + brow[rb - ct + 3][3 - r];
        t[ct][r] = tv;
        rm = fmaxf(rm, tv);
      }
    }
    rm = fmaxf(rm, __shfl_xor(rm, 16));
    rm = fmaxf(rm, __shfl_xor(rm, 32));
    float rs = 0.f;
    #pragma unroll
    for (int ct = 0; ct < 4; ++ct)
      #pragma unroll
      for (int r = 0; r < 4; ++r) {
        const float p = __expf(t[ct][r] - rm);
        t[ct][r] = p;
        rs += p;
      }
    rs += __shfl_xor(rs, 16);
    rs += __shfl_xor(rs, 32);
    const float rinv = 1.f / rs;

    bf16x4 ppk[4];
    #pragma unroll
    for (int ct = 0; ct < 4; ++ct) {
      f32x4 pv = {t[ct][0] * rinv, t[ct][1] * rinv, t[ct][2] * rinv, t[ct][3] * rinv};
      ppk[ct] = pack4(pv);
    }
    bf16x8 pa0 = cat8(ppk[0], ppk[1]);
    bf16x8 pa1 = cat8(ppk[2], ppk[3]);

    f32x4 o0 = fz, o1 = fz;
    o0 = MFMA16(vav[0][0], pa0, o0);
    o0 = MFMA16(vav[0][1], pa1, o0);
    o1 = MFMA16(vav[1][0], pa0, o1);
    o1 = MFMA16(vav[1][1], pa1, o1);
    *(bf16x4*)&ao[(rb * 16 + li) * XWA + hq * 32 + g * 4]      = pack4(o0);
    *(bf16x4*)&ao[(rb * 16 + li) * XWA + hq * 32 + 16 + g * 4] = pack4(o1);
  }
}

__device__ inline void proj_phase(const __bf16* __restrict__ ao, const __bf16* __restrict__ wp,
                                  const float* __restrict__ proj_b, const LaneCtx& L,
                                  int w0, float* __restrict__ out) {
  const f32x4 fz = {0.f, 0.f, 0.f, 0.f};
  const int li = L.li, g = L.g, wv = L.hq;
  f32x4 pacc[2][4];
  #pragma unroll
  for (int i = 0; i < 2; ++i)
    #pragma unroll
    for (int rt = 0; rt < 4; ++rt) pacc[i][rt] = fz;
  #pragma unroll
  for (int kk = 0; kk < 6; ++kk) {
    const int k0 = kk * 32 + g * 8;
    bf16x8 af[4];
    #pragma unroll
    for (int rt = 0; rt < 4; ++rt)
      af[rt] = *(const bf16x8*)&ao[(rt * 16 + li) * XWA + k0];
    #pragma unroll
    for (int i = 0; i < 2; ++i) {
      const int c = (wv * 2 + i) * 16 + li;
      bf16x8 bf = *(const bf16x8*)(wp + (size_t)c * Cdim + k0);
      #pragma unroll
      for (int rt = 0; rt < 4; ++rt)
        pacc[i][rt] = MFMA16(af[rt], bf, pacc[i][rt]);
    }
  }
  #pragma unroll
  for (int i = 0; i < 2; ++i) {
    const int c = (wv * 2 + i) * 16 + li;
    const float pb = proj_b[c];
    #pragma unroll
    for (int rt = 0; rt < 4; ++rt) {
      const int d = L.d0 + rt, hs = L.h0 + g;
      if (d < Dd && hs < Hh) {
        f32x4 vv = {pacc[i][rt][0] + pb, pacc[i][rt][1] + pb,
                    pacc[i][rt][2] + pb, pacc[i][rt][3] + pb};
        *(f32x4*)(out + ((size_t)(L.b * Cdim + c) * Dd + d) * HWst + hs * Wl + w0) = vv;
      }
    }
  }
}

__global__ __launch_bounds__(384, 4) void fused_kernel(
    const float* __restrict__ x, const float* __restrict__ qkv_b,
    const __bf16* __restrict__ wq, const __bf16* __restrict__ wp,
    const float* __restrict__ proj_b, const float* __restrict__ rpbt,
    float* __restrict__ out)
{
  __shared__ __bf16 regA[REGE];   // 27648 B
  __shared__ __bf16 regB[REGE];   // 27648 B   (total 55296 -> 2 blocks/CU)
  LaneCtx L;
  L.tid = threadIdx.x;
  const int lane = L.tid & 63;
  L.li = lane & 15; L.g = lane >> 4; L.hq = L.tid >> 6;
  const int bid = blockIdx.x;
  const int pid = (bid & 7) * (NPAIR / 8) + (bid >> 3);   // XCD-aware bijective (1728=8*216)
  const int wid0 = pid * 2;
  L.b = wid0 / NWIN_PER_B;
  const int wr = wid0 % NWIN_PER_B;
  L.d0 = (wr / 144) * 4; L.h0 = ((wr / 12) % 12) * 4;
  const int w0 = (wr % 12) * 4;       // window 1 is w0 + 4 (same d,h row: wr%12 is even)

  // per-lane bias registers (same for both windows)
  const int hbase = ((L.li >> 2) - L.g + 3) * 7 + (L.li & 3) + 3;
  float brow[7][4];
  {
    const float* rp = rpbt + L.hq * 343 + hbase - 3;
    #pragma unroll
    for (int dd = 0; dd < 7; ++dd)
      #pragma unroll
      for (int j = 0; j < 4; ++j)
        brow[dd][j] = rp[dd * 49 + j];
  }

  bf16x8 qfv[4], kfv[4], vav[2][2];

  // ---- window 0: xw=A, scratch=B ----
  stage_x(x, regA, L, w0);
  __syncthreads();
  gemm_qkv(regA, regB, qkv_b, wq, L, qfv, kfv, vav);
  __syncthreads();                       // all xw(A) reads done; A becomes ao
  attn_phase(regA, L, brow, qfv, kfv, vav);
  __syncthreads();                       // ao(A) complete
  proj_phase(regA, wp, proj_b, L, w0, out);
  // stage window 1 into B (B's repack data dead; no barrier -> overlaps proj above at wave level)
  stage_x(x, regB, L, w0 + 4);
  __syncthreads();                       // proj(A) + stage(B) complete everywhere

  // ---- window 1: xw=B, scratch=A ----
  gemm_qkv(regB, regA, qkv_b, wq, L, qfv, kfv, vav);
  __syncthreads();
  attn_phase(regB, L, brow, qfv, kfv, vav);
  __syncthreads();
  proj_phase(regB, wp, proj_b, L, w0 + 4, out);
}

// ============ Fallback: fused single-kernel (R3, f32 weights) ============
constexpr int XW_LD = 200, QK_LD = 36, VT_LD = 68, P_LDF = 68;
constexpr int XW_OFF  = 0;
constexpr int Q_OFF   = 25600;
constexpr int K_OFF   = Q_OFF + 27648;
constexpr int VT_OFF  = K_OFF + 27648;
constexpr int P_OFF   = VT_OFF + 26112;
constexpr int RPB_OFF = P_OFF + 26112;
constexpr int LDS_TOTAL = RPB_OFF + 8256;

__global__ __launch_bounds__(768, 3) void winattn_fused(
    const float* __restrict__ x, const float* __restrict__ qkv_w,
    const float* __restrict__ qkv_b, const float* __restrict__ proj_w,
    const float* __restrict__ proj_b, const float* __restrict__ rpb,
    float* __restrict__ out)
{
  extern __shared__ __align__(16) char smem[];
  __bf16* xw  = (__bf16*)(smem + XW_OFF);
  __bf16* qs  = (__bf16*)(smem + Q_OFF);
  __bf16* ks  = (__bf16*)(smem + K_OFF);
  __bf16* vt  = (__bf16*)(smem + VT_OFF);
  __bf16* pl  = (__bf16*)(smem + P_OFF);
  float*  rps = (float*)(smem + RPB_OFF);
  const f32x4 fz = {0.f, 0.f, 0.f, 0.f};
  const int tid = threadIdx.x, lane = tid & 63, wv = tid >> 6;
  const int hq = wv >> 1, half = wv & 1, li = lane & 15, g = lane >> 4;
  const int bid = blockIdx.x;
  const int wid = (bid & 7) * (NBLK / 8) + (bid >> 3);
  const int b = wid / NWIN_PER_B, wr = wid % NWIN_PER_B;
  const int d0 = (wr / 144) * 4, h0 = ((wr / 12) % 12) * 4, w0 = (wr % 12) * 4;
  for (int i = tid; i < 343 * NHd; i += 768) rps[i] = rpb[i];
  #pragma unroll
  for (int rep = 0; rep < 4; ++rep) {
    const int task = rep * 768 + tid;
    const int c = task % Cdim, ph = task / Cdim;
    const int dd = ph >> 2, hh2 = ph & 3;
    const int d = d0 + dd, hsp = h0 + hh2;
    f32x4 v = fz;
    if (d < Dd && hsp < Hh)
      v = *(const f32x4*)(x + ((size_t)(b * Cdim + c) * Dd + d) * HWst + hsp * Wl + w0);
    const int nb = (dd * 16 + hh2 * 4) * XW_LD + c;
    xw[nb] = (__bf16)v[0]; xw[nb + XW_LD] = (__bf16)v[1];
    xw[nb + 2 * XW_LD] = (__bf16)v[2]; xw[nb + 3 * XW_LD] = (__bf16)v[3];
  }
  __syncthreads();
  {
    f32x4 acc[6][2];
    #pragma unroll
    for (int it = 0; it < 6; ++it)
      #pragma unroll
      for (int rr = 0; rr < 2; ++rr) acc[it][rr] = fz;
    #pragma unroll
    for (int kk = 0; kk < 6; ++kk) {
      const int k0 = kk * 32 + g * 8;
      bf16x8 af[2];
      #pragma unroll
      for (int rr = 0; rr < 2; ++rr)
        af[rr] = *(const bf16x8*)&xw[((half * 2 + rr) * 16 + li) * XW_LD + k0];
      #pragma unroll
      for (int it = 0; it < 6; ++it) {
        const int T = (it >> 1) * 12 + hq * 2 + (it & 1);
        const int j = T * 16 + li;
        bf16x8 bf = cvt8(qkv_w + j * Cdim + k0);
        #pragma unroll
        for (int rr = 0; rr < 2; ++rr) acc[it][rr] = MFMA16(af[rr], bf, acc[it][rr]);
      }
    }
    #pragma unroll
    for (int it = 0; it < 6; ++it) {
      const int part = it >> 1, e16 = (it & 1) * 16;
      const int j0 = (part * 12 + hq * 2 + (it & 1)) * 16;
      const float qb = qkv_b[j0 + li];
      #pragma unroll
      for (int rr = 0; rr < 2; ++rr) {
        const int rb = half * 2 + rr;
        #pragma unroll
        for (int r = 0; r < 4; ++r) {
          const float val = acc[it][rr][r] + qb;
          const int n = rb * 16 + g * 4 + r;
          if (part == 0)      qs[(hq * 64 + n) * QK_LD + e16 + li] = (__bf16)val;
          else if (part == 1) ks[(hq * 64 + n) * QK_LD + e16 + li] = (__bf16)val;
          else                vt[(hq * 32 + e16 + li) * VT_LD + n] = (__bf16)val;
        }
      }
    }
  }
  __syncthreads();
  {
    __bf16* pw = pl + wv * 16 * P_LDF;
    #pragma unroll 1
    for (int rr = 0; rr < 2; ++rr) {
      const int rb = half * 2 + rr;
      bf16x8 aq = *(const bf16x8*)&qs[(hq * 64 + rb * 16 + li) * QK_LD + g * 8];
      f32x4 s[4];
      #pragma unroll
      for (int ct = 0; ct < 4; ++ct) {
        bf16x8 bk = *(const bf16x8*)&ks[(hq * 64 + ct * 16 + li) * QK_LD + g * 8];
        s[ct] = MFMA16(aq, bk, fz);
      }
      float t[4][4], rm[4] = {-3e38f, -3e38f, -3e38f, -3e38f};
      #pragma unroll
      for (int ct = 0; ct < 4; ++ct) {
        #pragma unroll
        for (int r = 0; r < 4; ++r) {
          const int idx = (rb - ct + 3) * 49 + (g - (li >> 2) + 3) * 7 + (r - (li & 3) + 3);
          const float tv = s[ct][r] * SCALE + rps[idx * NHd + hq];
          t[ct][r] = tv;
          rm[r] = fmaxf(rm[r], tv);
        }
      }
      #pragma unroll
      for (int r = 0; r < 4; ++r) {
        rm[r] = fmaxf(rm[r], __shfl_xor(rm[r], 1, 16));
        rm[r] = fmaxf(rm[r], __shfl_xor(rm[r], 2, 16));
        rm[r] = fmaxf(rm[r], __shfl_xor(rm[r], 4, 16));
        rm[r] = fmaxf(rm[r], __shfl_xor(rm[r], 8, 16));
      }
      float rs[4] = {0, 0, 0, 0};
      #pragma unroll
      for (int ct = 0; ct < 4; ++ct)
        #pragma unroll
        for (int r = 0; r < 4; ++r) {
          const float p = __expf(t[ct][r] - rm[r]);
          t[ct][r] = p; rs[r] += p;
        }
      #pragma unroll
      for (int r = 0; r < 4; ++r) {
        rs[r] += __shfl_xor(rs[r], 1, 16);
        rs[r] += __shfl_xor(rs[r], 2, 16);
        rs[r] += __shfl_xor(rs[r], 4, 16);
        rs[r] += __shfl_xor(rs[r], 8, 16);
      }
      #pragma unroll
      for (int ct = 0; ct < 4; ++ct)
        #pragma unroll
        for (int r = 0; r < 4; ++r)
          pw[(g * 4 + r) * P_LDF + ct * 16 + li] = (__bf16)t[ct][r];
      f32x4 o[2] = {fz, fz};
      #pragma unroll
      for (int kk = 0; kk < 2; ++kk) {
        bf16x8 ap = *(const bf16x8*)&pw[li * P_LDF + kk * 32 + g * 8];
        #pragma unroll
        for (int ct = 0; ct < 2; ++ct) {
          bf16x8 bv = *(const bf16x8*)&vt[(hq * 32 + ct * 16 + li) * VT_LD + kk * 32 + g * 8];
          o[ct] = MFMA16(ap, bv, o[ct]);
        }
      }
      float inv[4];
      #pragma unroll
      for (int r = 0; r < 4; ++r) inv[r] = 1.f / rs[r];
      #pragma unroll
      for (int ct = 0; ct < 2; ++ct)
        #pragma unroll
        for (int r = 0; r < 4; ++r)
          xw[(rb * 16 + g * 4 + r) * XW_LD + hq * 32 + ct * 16 + li] = (__bf16)(o[ct][r] * inv[r]);
    }
  }
  __syncthreads();
  {
    f32x4 acc[4];
    #pragma unroll
    for (int rt = 0; rt < 4; ++rt) acc[rt] = fz;
    const int c = wv * 16 + li;
    #pragma unroll
    for (int kk = 0; kk < 6; ++kk) {
      const int k0 = kk * 32 + g * 8;
      bf16x8 bf = cvt8(proj_w + c * Cdim + k0);
      #pragma unroll
      for (int rt = 0; rt < 4; ++rt) {
        bf16x8 af = *(const bf16x8*)&xw[(rt * 16 + li) * XW_LD + k0];
        acc[rt] = MFMA16(af, bf, acc[rt]);
      }
    }
    const float pb = proj_b[c];
    #pragma unroll
    for (int rt = 0; rt < 4; ++rt) {
      const int d = d0 + rt, hsp = h0 + g;
      if (d < Dd && hsp < Hh) {
        f32x4 vv = {acc[rt][0] + pb, acc[rt][1] + pb, acc[rt][2] + pb, acc[rt][3] + pb};
        *(f32x4*)(out + ((size_t)(b * Cdim + c) * Dd + d) * HWst + hsp * Wl + w0) = vv;
      }
    }
  }
}

extern "C" void kernel_launch(void* const* d_in, const int* in_sizes, int n_in,
                              void* d_out, int out_size, void* d_ws, size_t ws_size,
                              hipStream_t stream) {
  const float* x      = (const float*)d_in[0];
  const float* qkv_w  = (const float*)d_in[1];
  const float* qkv_b  = (const float*)d_in[2];
  const float* proj_w = (const float*)d_in[3];
  const float* proj_b = (const float*)d_in[4];
  const float* rpb    = (const float*)d_in[5];
  float* out = (float*)d_out;

  if (ws_size >= WS_SMALL) {
    __bf16* wsb  = (__bf16*)d_ws;
    __bf16* wq   = wsb + OFF_WQ;
    __bf16* wp   = wsb + OFF_WP;
    float*  rpbt = (float*)(wsb + OFF_RPBT);
    convert_w_kernel<<<(WQ_ELEMS + 255) / 256, 256, 0, stream>>>(qkv_w, proj_w, rpb, wq, wp, rpbt);
    fused_kernel<<<NPAIR, 384, 0, stream>>>(x, qkv_b, wq, wp, proj_b, rpbt, out);
  } else {
    (void)hipFuncSetAttribute(reinterpret_cast<const void*>(&winattn_fused),
                              hipFuncAttributeMaxDynamicSharedMemorySize, LDS_TOTAL);
    winattn_fused<<<NBLK, 768, LDS_TOTAL, stream>>>(
        x, qkv_w, qkv_b, proj_w, proj_b, rpb, out);
  }
}

// Round 19
// 292.147 us; speedup vs baseline: 1.3768x; 1.3768x over previous
//
#include <hip/hip_runtime.h>

typedef __bf16 bf16x8 __attribute__((ext_vector_type(8)));
typedef __bf16 bf16x4 __attribute__((ext_vector_type(4)));
typedef float  f32x4  __attribute__((ext_vector_type(4)));

#define MFMA16(a, b, c) __builtin_amdgcn_mfma_f32_16x16x32_bf16((a), (b), (c), 0, 0, 0)

// ---- problem geometry ----
constexpr int Cdim = 192, NHd = 6;
constexpr int Dd = 46, Hh = 47, Wl = 48;
constexpr int HWst = Hh * Wl;            // 2256
constexpr int NWIN_PER_B = 12 * 12 * 12; // 1728
constexpr int NBLK = 2 * NWIN_PER_B;     // 3456
constexpr float SCALE = 0.17677669529663687f;  // 32^-0.5

// ---- workspace layout: only converted weights + transposed bias table ----
constexpr int WQ_ELEMS = 576 * 192;
constexpr int WP_ELEMS = 192 * 192;
constexpr size_t OFF_WQ   = 0;
constexpr size_t OFF_WP   = OFF_WQ + WQ_ELEMS;
constexpr size_t OFF_RPBT = OFF_WP + WP_ELEMS;          // f32[6][343]
constexpr size_t WS_SMALL = (OFF_RPBT + 4128) * 2;      // ~300 KB

__device__ inline bf16x8 cvt8(const float* __restrict__ p) {
  f32x4 u0 = *(const f32x4*)p;
  f32x4 u1 = *(const f32x4*)(p + 4);
  bf16x8 r;
  r[0] = (__bf16)u0[0]; r[1] = (__bf16)u0[1]; r[2] = (__bf16)u0[2]; r[3] = (__bf16)u0[3];
  r[4] = (__bf16)u1[0]; r[5] = (__bf16)u1[1]; r[6] = (__bf16)u1[2]; r[7] = (__bf16)u1[3];
  return r;
}

__global__ __launch_bounds__(256) void convert_w_kernel(
    const float* __restrict__ qkv_w, const float* __restrict__ proj_w,
    const float* __restrict__ rpb,
    __bf16* __restrict__ wq, __bf16* __restrict__ wp, float* __restrict__ rpbt) {
  const int i = blockIdx.x * 256 + threadIdx.x;
  if (i < WQ_ELEMS) wq[i] = (__bf16)qkv_w[i];
  if (i < WP_ELEMS) wp[i] = (__bf16)proj_w[i];
  if (i < 343 * NHd) {
    const int h = i / 343, idx = i % 343;
    rpbt[h * 343 + idx] = rpb[idx * NHd + h];
  }
}

// ============ Fused kernel: QKV GEMM + attention + proj, one window/block ============
// LDS: xw[64][200] (x tile, reused as ao) + 6 wave-private 2304-elem repack buffers.
constexpr int QKLD = 36;   // q/k buf row stride (bf16): 72 B  (8B-aligned frag reads)
constexpr int VLD  = 68;   // v buf row stride: 136 B
constexpr int PLD  = 72;   // pw row stride: 144 B (16B-aligned)
constexpr int BUFE = 2304; // elems per wave buffer (4608 B)

__global__ __launch_bounds__(384, 4) void fused_kernel(
    const float* __restrict__ x, const float* __restrict__ qkv_b,
    const __bf16* __restrict__ wq, const __bf16* __restrict__ wp,
    const float* __restrict__ proj_b, const float* __restrict__ rpbt,
    float* __restrict__ out)
{
  __shared__ __bf16 xw[64 * 200];        // 25600 B; becomes ao after barrier 2
  __shared__ __bf16 bufs[6 * BUFE];      // 27648 B
  const f32x4 fz = {0.f, 0.f, 0.f, 0.f};
  const int tid = threadIdx.x, lane = tid & 63, wv = tid >> 6;  // wv = head hq
  const int li = lane & 15, g = lane >> 4;
  const int hq = wv;
  const int bid = blockIdx.x;
  const int wid = (bid & 7) * (NBLK / 8) + (bid >> 3);   // XCD-aware bijective
  const int b = wid / NWIN_PER_B, wr = wid % NWIN_PER_B;
  const int d0 = (wr / 144) * 4, h0 = ((wr / 12) % 12) * 4, w0 = (wr % 12) * 4;

  // ---- stage x window -> bf16 [n][c] ----
  #pragma unroll
  for (int rep = 0; rep < 8; ++rep) {
    const int task = rep * 384 + tid;          // < 3072
    const int c = task % Cdim, ph = task / Cdim;
    const int dd = ph >> 2, hh = ph & 3;
    const int d = d0 + dd, hs = h0 + hh;
    f32x4 v = fz;
    if (d < Dd && hs < Hh)
      v = *(const f32x4*)(x + ((size_t)(b * Cdim + c) * Dd + d) * HWst + hs * Wl + w0);
    const int nb = (dd * 16 + hh * 4) * 200 + c;
    xw[nb]       = (__bf16)v[0];
    xw[nb + 200] = (__bf16)v[1];
    xw[nb + 400] = (__bf16)v[2];
    xw[nb + 600] = (__bf16)v[3];
  }
  __syncthreads();

  __bf16* buf = bufs + wv * BUFE;
  bf16x8 qfv[4], kfv[4], vav[2][2];

  // ---- q part: tiles {2hq, 2hq+1} (chans hq*32..+32), swapped orientation ----
  {
    f32x4 acc[2][4];
    #pragma unroll
    for (int i = 0; i < 2; ++i)
      #pragma unroll
      for (int t = 0; t < 4; ++t) acc[i][t] = fz;
    #pragma unroll
    for (int kk = 0; kk < 6; ++kk) {
      const int k0 = kk * 32 + g * 8;
      bf16x8 xf[4];
      #pragma unroll
      for (int nt = 0; nt < 4; ++nt)
        xf[nt] = *(const bf16x8*)&xw[(nt * 16 + li) * 200 + k0];
      #pragma unroll
      for (int i = 0; i < 2; ++i) {
        bf16x8 wf = *(const bf16x8*)(wq + (size_t)((hq * 2 + i) * 16 + li) * Cdim + k0);
        #pragma unroll
        for (int nt = 0; nt < 4; ++nt)
          acc[i][nt] = MFMA16(wf, xf[nt], acc[i][nt]);
      }
    }
    // C[chan g*4+r (tile i)][token nt*16+li] -> buf [64 tok][QKLD]
    #pragma unroll
    for (int i = 0; i < 2; ++i) {
      const f32x4 b4 = *(const f32x4*)(qkv_b + (hq * 2 + i) * 16 + g * 4);
      #pragma unroll
      for (int nt = 0; nt < 4; ++nt) {
        f32x4 val = (acc[i][nt] + b4) * SCALE;
        bf16x4 pk;
        pk[0] = (__bf16)val[0]; pk[1] = (__bf16)val[1];
        pk[2] = (__bf16)val[2]; pk[3] = (__bf16)val[3];
        *(bf16x4*)&buf[(nt * 16 + li) * QKLD + i * 16 + g * 4] = pk;
      }
    }
    #pragma unroll
    for (int t = 0; t < 4; ++t) {
      bf16x4 lo = *(const bf16x4*)&buf[(t * 16 + li) * QKLD + g * 8];
      bf16x4 hi = *(const bf16x4*)&buf[(t * 16 + li) * QKLD + g * 8 + 4];
      bf16x8 r;
      r[0] = lo[0]; r[1] = lo[1]; r[2] = lo[2]; r[3] = lo[3];
      r[4] = hi[0]; r[5] = hi[1]; r[6] = hi[2]; r[7] = hi[3];
      qfv[t] = r;
    }
  }

  // ---- k part ----
  {
    f32x4 acc[2][4];
    #pragma unroll
    for (int i = 0; i < 2; ++i)
      #pragma unroll
      for (int t = 0; t < 4; ++t) acc[i][t] = fz;
    #pragma unroll
    for (int kk = 0; kk < 6; ++kk) {
      const int k0 = kk * 32 + g * 8;
      bf16x8 xf[4];
      #pragma unroll
      for (int nt = 0; nt < 4; ++nt)
        xf[nt] = *(const bf16x8*)&xw[(nt * 16 + li) * 200 + k0];
      #pragma unroll
      for (int i = 0; i < 2; ++i) {
        bf16x8 wf = *(const bf16x8*)(wq + (size_t)(192 + (hq * 2 + i) * 16 + li) * Cdim + k0);
        #pragma unroll
        for (int nt = 0; nt < 4; ++nt)
          acc[i][nt] = MFMA16(wf, xf[nt], acc[i][nt]);
      }
    }
    #pragma unroll
    for (int i = 0; i < 2; ++i) {
      const f32x4 b4 = *(const f32x4*)(qkv_b + 192 + (hq * 2 + i) * 16 + g * 4);
      #pragma unroll
      for (int nt = 0; nt < 4; ++nt) {
        f32x4 val = acc[i][nt] + b4;
        bf16x4 pk;
        pk[0] = (__bf16)val[0]; pk[1] = (__bf16)val[1];
        pk[2] = (__bf16)val[2]; pk[3] = (__bf16)val[3];
        *(bf16x4*)&buf[(nt * 16 + li) * QKLD + i * 16 + g * 4] = pk;
      }
    }
    #pragma unroll
    for (int t = 0; t < 4; ++t) {
      bf16x4 lo = *(const bf16x4*)&buf[(t * 16 + li) * QKLD + g * 8];
      bf16x4 hi = *(const bf16x4*)&buf[(t * 16 + li) * QKLD + g * 8 + 4];
      bf16x8 r;
      r[0] = lo[0]; r[1] = lo[1]; r[2] = lo[2]; r[3] = lo[3];
      r[4] = hi[0]; r[5] = hi[1]; r[6] = hi[2]; r[7] = hi[3];
      kfv[t] = r;
    }
  }

  // ---- v part: original orientation -> C[token g*4+r (rowtile rt)][chan tile*16+li] ----
  {
    f32x4 acc[2][4];
    #pragma unroll
    for (int i = 0; i < 2; ++i)
      #pragma unroll
      for (int t = 0; t < 4; ++t) acc[i][t] = fz;
    #pragma unroll
    for (int kk = 0; kk < 6; ++kk) {
      const int k0 = kk * 32 + g * 8;
      bf16x8 xf[4];
      #pragma unroll
      for (int rt = 0; rt < 4; ++rt)
        xf[rt] = *(const bf16x8*)&xw[(rt * 16 + li) * 200 + k0];
      #pragma unroll
      for (int i = 0; i < 2; ++i) {
        bf16x8 wf = *(const bf16x8*)(wq + (size_t)(384 + (hq * 2 + i) * 16 + li) * Cdim + k0);
        #pragma unroll
        for (int rt = 0; rt < 4; ++rt)
          acc[i][rt] = MFMA16(xf[rt], wf, acc[i][rt]);
      }
    }
    // lane li = chan (i*16+li), token rt*16+g*4+r  -> buf [32 chan][VLD]
    #pragma unroll
    for (int i = 0; i < 2; ++i) {
      const float bias = qkv_b[384 + (hq * 2 + i) * 16 + li];
      #pragma unroll
      for (int rt = 0; rt < 4; ++rt) {
        bf16x4 pk;
        pk[0] = (__bf16)(acc[i][rt][0] + bias);
        pk[1] = (__bf16)(acc[i][rt][1] + bias);
        pk[2] = (__bf16)(acc[i][rt][2] + bias);
        pk[3] = (__bf16)(acc[i][rt][3] + bias);
        *(bf16x4*)&buf[(i * 16 + li) * VLD + rt * 16 + g * 4] = pk;
      }
    }
    #pragma unroll
    for (int rt = 0; rt < 2; ++rt)
      #pragma unroll
      for (int kk = 0; kk < 2; ++kk) {
        bf16x4 lo = *(const bf16x4*)&buf[(rt * 16 + li) * VLD + kk * 32 + g * 8];
        bf16x4 hi = *(const bf16x4*)&buf[(rt * 16 + li) * VLD + kk * 32 + g * 8 + 4];
        bf16x8 r;
        r[0] = lo[0]; r[1] = lo[1]; r[2] = lo[2]; r[3] = lo[3];
        r[4] = hi[0]; r[5] = hi[1]; r[6] = hi[2]; r[7] = hi[3];
        vav[rt][kk] = r;
      }
  }
  __syncthreads();   // all xw reads done; xw becomes ao

  __bf16* ao = xw;   // [64][200]

  // per-lane bias registers
  const int hbase = ((li >> 2) - g + 3) * 7 + (li & 3) + 3;
  float brow[7][4];
  {
    const float* rp = rpbt + hq * 343 + hbase - 3;
    #pragma unroll
    for (int dd = 0; dd < 7; ++dd)
      #pragma unroll
      for (int j = 0; j < 4; ++j)
        brow[dd][j] = rp[dd * 49 + j];
  }

  __bf16* pw = buf;  // [16][PLD] inside wave buffer

  #pragma unroll
  for (int rb = 0; rb < 4; ++rb) {
    f32x4 s[4];
    #pragma unroll
    for (int ct = 0; ct < 4; ++ct) s[ct] = MFMA16(kfv[ct], qfv[rb], fz);

    float t[4][4];
    float rm = -3e38f;
    #pragma unroll
    for (int ct = 0; ct < 4; ++ct) {
      #pragma unroll
      for (int r = 0; r < 4; ++r) {
        const float tv = s[ct][r] + brow[rb - ct + 3][3 - r];
        t[ct][r] = tv;
        rm = fmaxf(rm, tv);
      }
    }
    rm = fmaxf(rm, __shfl_xor(rm, 16));
    rm = fmaxf(rm, __shfl_xor(rm, 32));
    float rs = 0.f;
    #pragma unroll
    for (int ct = 0; ct < 4; ++ct)
      #pragma unroll
      for (int r = 0; r < 4; ++r) {
        const float p = __expf(t[ct][r] - rm);
        t[ct][r] = p;
        rs += p;
      }
    rs += __shfl_xor(rs, 16);
    rs += __shfl_xor(rs, 32);
    const float rinv = 1.f / rs;

    // normalized P -> pw[query][key]
    #pragma unroll
    for (int ct = 0; ct < 4; ++ct) {
      bf16x4 pk;
      pk[0] = (__bf16)(t[ct][0] * rinv);
      pk[1] = (__bf16)(t[ct][1] * rinv);
      pk[2] = (__bf16)(t[ct][2] * rinv);
      pk[3] = (__bf16)(t[ct][3] * rinv);
      *(bf16x4*)&pw[li * PLD + ct * 16 + g * 4] = pk;
    }
    bf16x8 pa0 = *(const bf16x8*)&pw[li * PLD + g * 8];
    bf16x8 pa1 = *(const bf16x8*)&pw[li * PLD + 32 + g * 8];
    f32x4 o0 = fz, o1 = fz;
    o0 = MFMA16(vav[0][0], pa0, o0);
    o0 = MFMA16(vav[0][1], pa1, o0);
    o1 = MFMA16(vav[1][0], pa0, o1);
    o1 = MFMA16(vav[1][1], pa1, o1);
    #pragma unroll
    for (int rt = 0; rt < 2; ++rt) {
      const f32x4 o = rt ? o1 : o0;
      bf16x4 pk;
      pk[0] = (__bf16)o[0]; pk[1] = (__bf16)o[1];
      pk[2] = (__bf16)o[2]; pk[3] = (__bf16)o[3];
      *(bf16x4*)&ao[(rb * 16 + li) * 200 + hq * 32 + rt * 16 + g * 4] = pk;
    }
  }
  __syncthreads();

  // ---- proj: wave wv owns col tiles {wv*2, wv*2+1} ----
  f32x4 pacc[2][4];
  #pragma unroll
  for (int i = 0; i < 2; ++i)
    #pragma unroll
    for (int rt = 0; rt < 4; ++rt) pacc[i][rt] = fz;
  #pragma unroll
  for (int kk = 0; kk < 6; ++kk) {
    const int k0 = kk * 32 + g * 8;
    bf16x8 af[4];
    #pragma unroll
    for (int rt = 0; rt < 4; ++rt)
      af[rt] = *(const bf16x8*)&ao[(rt * 16 + li) * 200 + k0];
    #pragma unroll
    for (int i = 0; i < 2; ++i) {
      const int c = (wv * 2 + i) * 16 + li;
      bf16x8 bf = *(const bf16x8*)(wp + (size_t)c * Cdim + k0);
      #pragma unroll
      for (int rt = 0; rt < 4; ++rt)
        pacc[i][rt] = MFMA16(af[rt], bf, pacc[i][rt]);
    }
  }
  #pragma unroll
  for (int i = 0; i < 2; ++i) {
    const int c = (wv * 2 + i) * 16 + li;
    const float pb = proj_b[c];
    #pragma unroll
    for (int rt = 0; rt < 4; ++rt) {
      const int d = d0 + rt, hs = h0 + g;
      if (d < Dd && hs < Hh) {
        f32x4 vv = {pacc[i][rt][0] + pb, pacc[i][rt][1] + pb,
                    pacc[i][rt][2] + pb, pacc[i][rt][3] + pb};
        *(f32x4*)(out + ((size_t)(b * Cdim + c) * Dd + d) * HWst + hs * Wl + w0) = vv;
      }
    }
  }
}

// ============ Fallback: fused single-kernel (R3, f32 weights) ============
constexpr int XW_LD = 200, QK_LD = 36, VT_LD = 68, P_LDF = 68;
constexpr int XW_OFF  = 0;
constexpr int Q_OFF   = 25600;
constexpr int K_OFF   = Q_OFF + 27648;
constexpr int VT_OFF  = K_OFF + 27648;
constexpr int P_OFF   = VT_OFF + 26112;
constexpr int RPB_OFF = P_OFF + 26112;
constexpr int LDS_TOTAL = RPB_OFF + 8256;

__global__ __launch_bounds__(768, 3) void winattn_fused(
    const float* __restrict__ x, const float* __restrict__ qkv_w,
    const float* __restrict__ qkv_b, const float* __restrict__ proj_w,
    const float* __restrict__ proj_b, const float* __restrict__ rpb,
    float* __restrict__ out)
{
  extern __shared__ __align__(16) char smem[];
  __bf16* xw  = (__bf16*)(smem + XW_OFF);
  __bf16* qs  = (__bf16*)(smem + Q_OFF);
  __bf16* ks  = (__bf16*)(smem + K_OFF);
  __bf16* vt  = (__bf16*)(smem + VT_OFF);
  __bf16* pl  = (__bf16*)(smem + P_OFF);
  float*  rps = (float*)(smem + RPB_OFF);
  const f32x4 fz = {0.f, 0.f, 0.f, 0.f};
  const int tid = threadIdx.x, lane = tid & 63, wv = tid >> 6;
  const int hq = wv >> 1, half = wv & 1, li = lane & 15, g = lane >> 4;
  const int bid = blockIdx.x;
  const int wid = (bid & 7) * (NBLK / 8) + (bid >> 3);
  const int b = wid / NWIN_PER_B, wr = wid % NWIN_PER_B;
  const int d0 = (wr / 144) * 4, h0 = ((wr / 12) % 12) * 4, w0 = (wr % 12) * 4;
  for (int i = tid; i < 343 * NHd; i += 768) rps[i] = rpb[i];
  #pragma unroll
  for (int rep = 0; rep < 4; ++rep) {
    const int task = rep * 768 + tid;
    const int c = task % Cdim, ph = task / Cdim;
    const int dd = ph >> 2, hh2 = ph & 3;
    const int d = d0 + dd, hsp = h0 + hh2;
    f32x4 v = fz;
    if (d < Dd && hsp < Hh)
      v = *(const f32x4*)(x + ((size_t)(b * Cdim + c) * Dd + d) * HWst + hsp * Wl + w0);
    const int nb = (dd * 16 + hh2 * 4) * XW_LD + c;
    xw[nb] = (__bf16)v[0]; xw[nb + XW_LD] = (__bf16)v[1];
    xw[nb + 2 * XW_LD] = (__bf16)v[2]; xw[nb + 3 * XW_LD] = (__bf16)v[3];
  }
  __syncthreads();
  {
    f32x4 acc[6][2];
    #pragma unroll
    for (int it = 0; it < 6; ++it)
      #pragma unroll
      for (int rr = 0; rr < 2; ++rr) acc[it][rr] = fz;
    #pragma unroll
    for (int kk = 0; kk < 6; ++kk) {
      const int k0 = kk * 32 + g * 8;
      bf16x8 af[2];
      #pragma unroll
      for (int rr = 0; rr < 2; ++rr)
        af[rr] = *(const bf16x8*)&xw[((half * 2 + rr) * 16 + li) * XW_LD + k0];
      #pragma unroll
      for (int it = 0; it < 6; ++it) {
        const int T = (it >> 1) * 12 + hq * 2 + (it & 1);
        const int j = T * 16 + li;
        bf16x8 bf = cvt8(qkv_w + j * Cdim + k0);
        #pragma unroll
        for (int rr = 0; rr < 2; ++rr) acc[it][rr] = MFMA16(af[rr], bf, acc[it][rr]);
      }
    }
    #pragma unroll
    for (int it = 0; it < 6; ++it) {
      const int part = it >> 1, e16 = (it & 1) * 16;
      const int j0 = (part * 12 + hq * 2 + (it & 1)) * 16;
      const float qb = qkv_b[j0 + li];
      #pragma unroll
      for (int rr = 0; rr < 2; ++rr) {
        const int rb = half * 2 + rr;
        #pragma unroll
        for (int r = 0; r < 4; ++r) {
          const float val = acc[it][rr][r] + qb;
          const int n = rb * 16 + g * 4 + r;
          if (part == 0)      qs[(hq * 64 + n) * QK_LD + e16 + li] = (__bf16)val;
          else if (part == 1) ks[(hq * 64 + n) * QK_LD + e16 + li] = (__bf16)val;
          else                vt[(hq * 32 + e16 + li) * VT_LD + n] = (__bf16)val;
        }
      }
    }
  }
  __syncthreads();
  {
    __bf16* pw = pl + wv * 16 * P_LDF;
    #pragma unroll 1
    for (int rr = 0; rr < 2; ++rr) {
      const int rb = half * 2 + rr;
      bf16x8 aq = *(const bf16x8*)&qs[(hq * 64 + rb * 16 + li) * QK_LD + g * 8];
      f32x4 s[4];
      #pragma unroll
      for (int ct = 0; ct < 4; ++ct) {
        bf16x8 bk = *(const bf16x8*)&ks[(hq * 64 + ct * 16 + li) * QK_LD + g * 8];
        s[ct] = MFMA16(aq, bk, fz);
      }
      float t[4][4], rm[4] = {-3e38f, -3e38f, -3e38f, -3e38f};
      #pragma unroll
      for (int ct = 0; ct < 4; ++ct) {
        #pragma unroll
        for (int r = 0; r < 4; ++r) {
          const int idx = (rb - ct + 3) * 49 + (g - (li >> 2) + 3) * 7 + (r - (li & 3) + 3);
          const float tv = s[ct][r] * SCALE + rps[idx * NHd + hq];
          t[ct][r] = tv;
          rm[r] = fmaxf(rm[r], tv);
        }
      }
      #pragma unroll
      for (int r = 0; r < 4; ++r) {
        rm[r] = fmaxf(rm[r], __shfl_xor(rm[r], 1, 16));
        rm[r] = fmaxf(rm[r], __shfl_xor(rm[r], 2, 16));
        rm[r] = fmaxf(rm[r], __shfl_xor(rm[r], 4, 16));
        rm[r] = fmaxf(rm[r], __shfl_xor(rm[r], 8, 16));
      }
      float rs[4] = {0, 0, 0, 0};
      #pragma unroll
      for (int ct = 0; ct < 4; ++ct)
        #pragma unroll
        for (int r = 0; r < 4; ++r) {
          const float p = __expf(t[ct][r] - rm[r]);
          t[ct][r] = p; rs[r] += p;
        }
      #pragma unroll
      for (int r = 0; r < 4; ++r) {
        rs[r] += __shfl_xor(rs[r], 1, 16);
        rs[r] += __shfl_xor(rs[r], 2, 16);
        rs[r] += __shfl_xor(rs[r], 4, 16);
        rs[r] += __shfl_xor(rs[r], 8, 16);
      }
      #pragma unroll
      for (int ct = 0; ct < 4; ++ct)
        #pragma unroll
        for (int r = 0; r < 4; ++r)
          pw[(g * 4 + r) * P_LDF + ct * 16 + li] = (__bf16)t[ct][r];
      f32x4 o[2] = {fz, fz};
      #pragma unroll
      for (int kk = 0; kk < 2; ++kk) {
        bf16x8 ap = *(const bf16x8*)&pw[li * P_LDF + kk * 32 + g * 8];
        #pragma unroll
        for (int ct = 0; ct < 2; ++ct) {
          bf16x8 bv = *(const bf16x8*)&vt[(hq * 32 + ct * 16 + li) * VT_LD + kk * 32 + g * 8];
          o[ct] = MFMA16(ap, bv, o[ct]);
        }
      }
      float inv[4];
      #pragma unroll
      for (int r = 0; r < 4; ++r) inv[r] = 1.f / rs[r];
      #pragma unroll
      for (int ct = 0; ct < 2; ++ct)
        #pragma unroll
        for (int r = 0; r < 4; ++r)
          xw[(rb * 16 + g * 4 + r) * XW_LD + hq * 32 + ct * 16 + li] = (__bf16)(o[ct][r] * inv[r]);
    }
  }
  __syncthreads();
  {
    f32x4 acc[4];
    #pragma unroll
    for (int rt = 0; rt < 4; ++rt) acc[rt] = fz;
    const int c = wv * 16 + li;
    #pragma unroll
    for (int kk = 0; kk < 6; ++kk) {
      const int k0 = kk * 32 + g * 8;
      bf16x8 bf = cvt8(proj_w + c * Cdim + k0);
      #pragma unroll
      for (int rt = 0; rt < 4; ++rt) {
        bf16x8 af = *(const bf16x8*)&xw[(rt * 16 + li) * XW_LD + k0];
        acc[rt] = MFMA16(af, bf, acc[rt]);
      }
    }
    const float pb = proj_b[c];
    #pragma unroll
    for (int rt = 0; rt < 4; ++rt) {
      const int d = d0 + rt, hsp = h0 + g;
      if (d < Dd && hsp < Hh) {
        f32x4 vv = {acc[rt][0] + pb, acc[rt][1] + pb, acc[rt][2] + pb, acc[rt][3] + pb};
        *(f32x4*)(out + ((size_t)(b * Cdim + c) * Dd + d) * HWst + hsp * Wl + w0) = vv;
      }
    }
  }
}

extern "C" void kernel_launch(void* const* d_in, const int* in_sizes, int n_in,
                              void* d_out, int out_size, void* d_ws, size_t ws_size,
                              hipStream_t stream) {
  const float* x      = (const float*)d_in[0];
  const float* qkv_w  = (const float*)d_in[1];
  const float* qkv_b  = (const float*)d_in[2];
  const float* proj_w = (const float*)d_in[3];
  const float* proj_b = (const float*)d_in[4];
  const float* rpb    = (const float*)d_in[5];
  float* out = (float*)d_out;

  if (ws_size >= WS_SMALL) {
    __bf16* wsb  = (__bf16*)d_ws;
    __bf16* wq   = wsb + OFF_WQ;
    __bf16* wp   = wsb + OFF_WP;
    float*  rpbt = (float*)(wsb + OFF_RPBT);
    convert_w_kernel<<<(WQ_ELEMS + 255) / 256, 256, 0, stream>>>(qkv_w, proj_w, rpb, wq, wp, rpbt);
    fused_kernel<<<NBLK, 384, 0, stream>>>(x, qkv_b, wq, wp, proj_b, rpbt, out);
  } else {
    (void)hipFuncSetAttribute(reinterpret_cast<const void*>(&winattn_fused),
                              hipFuncAttributeMaxDynamicSharedMemorySize, LDS_TOTAL);
    winattn_fused<<<NBLK, 768, LDS_TOTAL, stream>>>(
        x, qkv_w, qkv_b, proj_w, proj_b, rpb, out);
  }
}